// Round 8
// baseline (376.031 us; speedup 1.0000x reference)
//
#include <hip/hip_runtime.h>
#include <math.h>

typedef __attribute__((ext_vector_type(2))) float f32x2;
typedef __attribute__((ext_vector_type(4))) float f32x4;

// Problem dims (fixed): (B=4, 1, D=160, H=192, W=192) f32
#define BDIM 4
#define DDIM 160
#define HDIM 192
#define WDIM 192
#define NTOT (BDIM * DDIM * HDIM * WDIM)

#define TH 16
#define TW 64
#define SEG 20               // output D-slices per block
#define NSEG (DDIM / SEG)    // 8
#define NS  (SEG + 6)        // 26 input slices
#define NTH 512

#define RHH (TH + 6)         // 22
#define RWW 70
#define NRAW (RHH * RWW)     // 1540

#define HBROW 576            // bytes per hb row (72 f32x2 slots)

template<int N> struct IC { static constexpr int v = N; };

__device__ __forceinline__ float rcp_fast(float x) {
#if __has_builtin(__builtin_amdgcn_rcpf)
    return __builtin_amdgcn_rcpf(x);
#else
    return 1.0f / x;
#endif
}

__global__ __launch_bounds__(NTH, 4)
void nq_main(const float* __restrict__ X,   // recon
             const float* __restrict__ Y,   // target
             float* __restrict__ acc)       // [0]=ssim_sum [1]=l1_num [2]=l1_den
{
    constexpr float Gc[7] = {
        0.03663285f, 0.11128076f, 0.21674532f, 0.27068215f,
        0.21674532f, 0.11128076f, 0.03663285f };
    constexpr float C1f = 4.0e-4f;   // (0.01*2)^2
    constexpr float C2f = 3.6e-3f;   // (0.03*2)^2

    // s/d basis; NO wb stage (W-blur goes straight to window registers).
    // raw + hb double-buffered, single barrier per step. 61.6 KB -> 2 blocks/CU.
    __shared__ __align__(16) f32x2 raw[2][NRAW];        // 24,640 B (s,d)
    __shared__ __align__(16) char  hbA[2][TH * HBROW];  // 18,432 B H-blur (s,d)
    __shared__ __align__(16) char  hbB[2][TH * HBROW];  // 18,432 B H-blur (s2,d2)
    __shared__ float red[NTH / 64][3];

    const int wt  = blockIdx.x;            // 0..2
    const int ht  = blockIdx.y;            // 0..11
    const int b   = blockIdx.z >> 3;       // 0..3
    const int seg = blockIdx.z & 7;        // 0..7
    const int h0 = ht * TH, w0 = wt * TW;
    const int dbase = seg * SEG;
    const long long bbase = (long long)b * (DDIM * HDIM * WDIM);
    const int t = threadIdx.x;

    // ---- raw-load invariants: 4 pts (1540 = 3*512 + 4) ----
    int goff[4]; bool ok[4], inter[4];
    #pragma unroll
    for (int i = 0; i < 4; ++i) {
        const int idx = (i < 3) ? (t + i * NTH) : (1536 + t);
        const int hh = idx / RWW, ww = idx - hh * RWW;
        const int h = h0 + hh - 3, w = w0 + ww - 3;
        bool o_ = ((unsigned)h < HDIM) && ((unsigned)w < WDIM);
        bool in_ = ((unsigned)(hh - 3) < TH) && ((unsigned)(ww - 3) < TW);
        if (i == 3) { o_ = o_ && (t < 4); in_ = false; }  // straggler rows never interior
        ok[i] = o_; inter[i] = in_;
        goff[i] = h * WDIM + w;
    }

    // ---- P2 invariants: H-blur items (1120 = 2*512 + 96) ----
    const int q0r = t / RWW,             q0w = t - q0r * RWW;
    const int q1r = (t + NTH) / RWW,     q1w = (t + NTH) - q1r * RWW;
    const int q2r = (t + 2 * NTH) / RWW, q2w = (t + 2 * NTH) - q2r * RWW;
    const bool q2on = t < (TH * RWW - 2 * NTH);   // t < 96

    // ---- P3' invariants: 2 adjacent output cols per thread ----
    const int p3r = t >> 5;              // row 0..15
    const int p3c = (t & 31) << 1;       // col 0,2,...,62
    const int p3x = (p3r & 1) << 3;      // hb XOR byte (break 8-way conflicts)

    float ssum = 0.f, l1n = 0.f, l1d = 0.f;
    f32x2 wA0[7], wA1[7], wB0[7], wB1[7];   // D-windows for the 2 pixels (56 VGPR)
    float pfs[4], pfd[4];                   // prefetched (s,d)

    auto loadslice = [&](int s) {        // prefetch raw slice s into regs; fused L1
        const int d_g = dbase - 3 + s;
        const bool dok = (unsigned)d_g < (unsigned)DDIM;
        const long long sb = bbase + (long long)d_g * (HDIM * WDIM);
        const bool l1on = (s >= 3) && (s <= SEG + 2);
        #pragma unroll
        for (int i = 0; i < 4; ++i) {
            const bool l = dok && ok[i];
            const float xv = l ? X[sb + goff[i]] : 0.f;
            const float yv = l ? Y[sb + goff[i]] : 0.f;
            if (l1on && inter[i]) {      // exact x,y used here
                const float wgt = (yv > -0.9f) ? 5.f : 1.f;
                l1n += wgt * fabsf(xv - yv);
                l1d += wgt;
            }
            pfs[i] = xv + yv;
            pfd[i] = xv - yv;
        }
    };

    auto commit = [&](int s) {           // write prefetched slice s to LDS
        const int rb = s & 1;
        raw[rb][t]           = (f32x2){pfs[0], pfd[0]};
        raw[rb][t + NTH]     = (f32x2){pfs[1], pfd[1]};
        raw[rb][t + 2 * NTH] = (f32x2){pfs[2], pfd[2]};
        if (t < 4) raw[rb][1536 + t] = (f32x2){pfs[3], pfd[3]};
    };

    auto p2item = [&](int rb, int r, int w) {
        f32x2 aA = {0.f, 0.f}, aB = {0.f, 0.f};
        #pragma unroll
        for (int k = 0; k < 7; ++k) {
            const f32x2 p = raw[rb][(r + k) * RWW + w];
            const float g = Gc[k];
            aA += g * p;                 // pk_fma
            aB += (g * p) * p;           // pk_mul + pk_fma
        }
        const int off = (r * HBROW + w * 8) ^ ((r & 1) << 3);
        *(f32x2*)(hbA[rb] + off) = aA;
        *(f32x2*)(hbB[rb] + off) = aB;
    };

    auto emitpx = [&](auto PPc2, f32x2 (&wAp)[7], f32x2 (&wBp)[7]) {
        constexpr int PP2 = PPc2.v;
        f32x2 mu = {0.f, 0.f}, e2 = {0.f, 0.f};
        #pragma unroll
        for (int k = 0; k < 7; ++k) {
            const int s = (PP2 + k) % 7;                // compile-time per unroll
            const float g = Gc[k];
            mu += g * wAp[s]; e2 += g * wBp[s];
        }
        const float P = mu.x * mu.x, Q = mu.y * mu.y;
        const float u  = 0.5f * (P + Q);
        const float v_ = 0.5f * (P - Q);
        const float a2 = 0.5f * (e2.x + e2.y);
        const float b2 = 0.5f * (e2.x - e2.y);
        const float num = (v_ + C1f) * (b2 - v_ + C2f);
        const float den = (u  + C1f) * (a2 - u  + C2f);
        ssum += num * rcp_fast(den);
    };

    // step ps: commit(ps+1); prefetch ps+2; P2(ps): raw->hb;
    // P3'(ps-1): hb -> window slot (ps-1)%7 (registers, no LDS stage);
    // emit output od = ps-7 when ps >= 7. ONE barrier per step.
    auto phase = [&](auto PPc, int it) {
        constexpr int PP = PPc.v;
        constexpr int SLOT = (PP + 6) % 7;           // (ps-1)%7
        const int ps = it * 7 + PP;
        const int par = ps & 1;

        if (ps <= NS - 2) commit(ps + 1);            // -> raw[(ps+1)&1]
        if (ps <= NS - 3) loadslice(ps + 2);         // lands during this step's compute

        if (ps <= NS - 1) {                          // P2: raw[ps&1] -> hb[ps&1]
            p2item(par, q0r, q0w);
            p2item(par, q1r, q1w);
            if (q2on) p2item(par, q2r, q2w);
        }
        if (ps >= 1 && ps <= NS) {                   // P3': hb[(ps-1)&1] -> window regs
            const int hp = par ^ 1;
            const char* bA = hbA[hp] + p3r * HBROW;
            const char* bB = hbB[hp] + p3r * HBROW;
            {
                f32x2 vA[8];
                #pragma unroll
                for (int j = 0; j < 8; ++j)
                    vA[j] = *(const f32x2*)(bA + (((p3c + j) * 8) ^ p3x));
                f32x2 a0 = {0.f, 0.f}, a1 = {0.f, 0.f};
                #pragma unroll
                for (int k = 0; k < 7; ++k) {
                    const float g = Gc[k];
                    a0 += g * vA[k]; a1 += g * vA[k + 1];
                }
                wA0[SLOT] = a0; wA1[SLOT] = a1;
            }
            {
                f32x2 vB[8];
                #pragma unroll
                for (int j = 0; j < 8; ++j)
                    vB[j] = *(const f32x2*)(bB + (((p3c + j) * 8) ^ p3x));
                f32x2 b0 = {0.f, 0.f}, b1 = {0.f, 0.f};
                #pragma unroll
                for (int k = 0; k < 7; ++k) {
                    const float g = Gc[k];
                    b0 += g * vB[k]; b1 += g * vB[k + 1];
                }
                wB0[SLOT] = b0; wB1[SLOT] = b1;
            }
            if (ps >= 7) {                           // emit od = ps-7 for both pixels
                emitpx(IC<PP>{}, wA0, wB0);
                emitpx(IC<PP>{}, wA1, wB1);
            }
        }
        __syncthreads();
    };

    // prologue: slice 0 committed, slice 1 prefetched into regs
    loadslice(0);
    commit(0);
    loadslice(1);
    __syncthreads();

    for (int it = 0; it < 4; ++it) {       // ps = 0..27 (27 is a no-op pad)
        phase(IC<0>{}, it); phase(IC<1>{}, it); phase(IC<2>{}, it);
        phase(IC<3>{}, it); phase(IC<4>{}, it); phase(IC<5>{}, it);
        phase(IC<6>{}, it);
    }

    // ---- block reduce + atomics ----
    #pragma unroll
    for (int off = 32; off > 0; off >>= 1) {
        ssum += __shfl_down(ssum, off, 64);
        l1n  += __shfl_down(l1n,  off, 64);
        l1d  += __shfl_down(l1d,  off, 64);
    }
    const int wave = t >> 6, lane = t & 63;
    if (lane == 0) { red[wave][0] = ssum; red[wave][1] = l1n; red[wave][2] = l1d; }
    __syncthreads();
    if (t == 0) {
        float s = 0.f, n = 0.f, dn = 0.f;
        #pragma unroll
        for (int i = 0; i < NTH / 64; ++i) {
            s += red[i][0]; n += red[i][1]; dn += red[i][2];
        }
        atomicAdd(&acc[0], s);
        atomicAdd(&acc[1], n);
        atomicAdd(&acc[2], dn);
    }
}

__global__ void nq_final(const float* __restrict__ acc,
                         const float* __restrict__ vq,
                         float* __restrict__ out)
{
    const float ssim_mean = acc[0] / (float)NTOT;
    out[0] = acc[1] / acc[2] + 0.5f * (1.0f - ssim_mean) + vq[0];
}

extern "C" void kernel_launch(void* const* d_in, const int* in_sizes, int n_in,
                              void* d_out, int out_size, void* d_ws, size_t ws_size,
                              hipStream_t stream)
{
    const float* X  = (const float*)d_in[0];  // recon
    const float* Y  = (const float*)d_in[1];  // target
    const float* vq = (const float*)d_in[2];  // scalar
    float* out = (float*)d_out;
    float* acc = (float*)d_ws;

    hipMemsetAsync(acc, 0, 3 * sizeof(float), stream);

    dim3 grid(WDIM / TW, HDIM / TH, BDIM * NSEG);   // 3 x 12 x 32 = 1152 blocks
    nq_main<<<grid, NTH, 0, stream>>>(X, Y, acc);
    nq_final<<<1, 1, 0, stream>>>(acc, vq, out);
}

// Round 9
// 198.609 us; speedup vs baseline: 1.8933x; 1.8933x over previous
//
#include <hip/hip_runtime.h>
#include <math.h>

typedef __attribute__((ext_vector_type(2))) float f32x2;

// Problem dims (fixed): (B=4, 1, D=160, H=192, W=192) f32
#define BDIM 4
#define DDIM 160
#define HDIM 192
#define WDIM 192
#define NTOT (BDIM * DDIM * HDIM * WDIM)

#define TH 8
#define TW 64
#define SEG 20               // output D-slices per block
#define NSEG (DDIM / SEG)    // 8
#define NS  (SEG + 6)        // 26 input slices
#define NTH 512

#define RHH (TH + 6)         // 14
#define RWW 70
#define NRAW (RHH * RWW)     // 980
#define HBS 72               // hb row stride (f32x2 elements)

template<int N> struct IC { static constexpr int v = N; };

__device__ __forceinline__ float rcp_fast(float x) {
#if __has_builtin(__builtin_amdgcn_rcpf)
    return __builtin_amdgcn_rcpf(x);
#else
    return 1.0f / x;
#endif
}

// Raw barrier: LDS visibility only (lgkmcnt), global prefetch loads stay
// in flight across it (their vmcnt waits are inserted at point of use).
#define STEP_BARRIER() do {                                   \
    asm volatile("s_waitcnt lgkmcnt(0)" ::: "memory");        \
    __builtin_amdgcn_s_barrier();                             \
} while (0)

__global__ __launch_bounds__(NTH, 4)
void nq_main(const float* __restrict__ X,   // recon
             const float* __restrict__ Y,   // target
             float* __restrict__ acc)       // [0]=ssim_sum [1]=l1_num [2]=l1_den
{
    constexpr float Gc[7] = {
        0.03663285f, 0.11128076f, 0.21674532f, 0.27068215f,
        0.21674532f, 0.11128076f, 0.03663285f };
    constexpr float C1f = 4.0e-4f;   // (0.01*2)^2
    constexpr float C2f = 3.6e-3f;   // (0.03*2)^2

    // s/d basis: raw (s,d) + two H-blurred packed planes; no wb stage.
    // All accesses stride-8B wave-linear -> no bank conflicts, no swizzle.
    // LDS = 34.3 KB; SGPR caps residency at 3 blocks/CU.
    __shared__ __align__(16) f32x2 raw[2][NRAW];      // 15,680 B (s,d)
    __shared__ __align__(16) f32x2 hbA[2][TH][HBS];   //  9,216 B (Hs, Hd)
    __shared__ __align__(16) f32x2 hbB[2][TH][HBS];   //  9,216 B (Hs2, Hd2)
    __shared__ float red[NTH / 64][3];

    const int wt  = blockIdx.x;            // 0..2
    const int ht  = blockIdx.y;            // 0..23
    const int b   = blockIdx.z >> 3;       // 0..3
    const int seg = blockIdx.z & 7;        // 0..7
    const int h0 = ht * TH, w0 = wt * TW;
    const int dbase = seg * SEG;
    const long long bbase = (long long)b * (DDIM * HDIM * WDIM);
    const int t = threadIdx.x;

    // ---- raw-load invariants: 2 pts/thread (980 = 512 + 468) ----
    int goff[2]; bool ok[2], inter[2];
    #pragma unroll
    for (int i = 0; i < 2; ++i) {
        const int idx = t + i * NTH;
        const int hh = idx / RWW, ww = idx - hh * RWW;
        const int h = h0 + hh - 3, w = w0 + ww - 3;
        bool o_ = ((unsigned)h < HDIM) && ((unsigned)w < WDIM);
        bool in_ = ((unsigned)(hh - 3) < TH) && ((unsigned)(ww - 3) < TW);
        if (i == 1 && idx >= NRAW) { o_ = false; in_ = false; }
        ok[i] = o_; inter[i] = in_;
        goff[i] = h * WDIM + w;
    }
    const bool has1 = (t + NTH) < NRAW;    // t < 468

    // ---- P2 invariants: H-blur items (560 = 512 + 48) ----
    const int q0r = t / RWW,         q0w = t - q0r * RWW;
    const int q1r = (t + NTH) / RWW, q1w = (t + NTH) - q1r * RWW;
    const bool q1on = t < (TH * RWW - NTH);            // t < 48

    // ---- P3/P4 invariants: 1 pixel per thread ----
    const int p4r = t >> 6;              // row 0..7
    const int p4c = t & 63;              // col 0..63

    float ssum = 0.f, l1n = 0.f, l1d = 0.f;
    f32x2 wA[7], wB[7];                  // D-window (28 VGPR), static slots
    float pfs[2], pfd[2];                // prefetched (s,d)

    auto loadslice = [&](int s) {        // issue global loads; fused weighted-L1
        const int d_g = dbase - 3 + s;
        const bool dok = (unsigned)d_g < (unsigned)DDIM;
        const long long sb = bbase + (long long)d_g * (HDIM * WDIM);
        const bool l1on = (s >= 3) && (s <= SEG + 2);
        #pragma unroll
        for (int i = 0; i < 2; ++i) {
            const bool l = dok && ok[i];
            const float xv = l ? X[sb + goff[i]] : 0.f;
            const float yv = l ? Y[sb + goff[i]] : 0.f;
            if (l1on && inter[i]) {      // exact x,y here
                const float wgt = (yv > -0.9f) ? 5.f : 1.f;
                l1n += wgt * fabsf(xv - yv);
                l1d += wgt;
            }
            pfs[i] = xv + yv;
            pfd[i] = xv - yv;
        }
    };

    auto commit = [&](int s) {           // write prefetched slice s to LDS
        const int rb = s & 1;
        raw[rb][t] = (f32x2){pfs[0], pfd[0]};
        if (has1) raw[rb][t + NTH] = (f32x2){pfs[1], pfd[1]};
    };

    auto p2item = [&](int rb, int r, int w) {
        f32x2 aA = {0.f, 0.f}, aB = {0.f, 0.f};
        #pragma unroll
        for (int k = 0; k < 7; ++k) {
            const f32x2 p = raw[rb][(r + k) * RWW + w];
            const float g = Gc[k];
            aA += g * p;                 // pk_fma
            aB += (g * p) * p;           // pk_mul + pk_fma
        }
        hbA[rb][r][w] = aA;
        hbB[rb][r][w] = aB;
    };

    // step ps: commit(ps+1); issue loads for ps+2; P2(ps): raw->hb;
    // P3(ps-1): hb -> window slot (ps-1)%7 (registers, no wb stage);
    // emit output od = ps-7 when ps in [7, NS]. ONE raw barrier per step.
    auto phase = [&](auto PPc, int it) {
        constexpr int PP = PPc.v;
        constexpr int SLOT = (PP + 6) % 7;           // (ps-1)%7
        const int ps = it * 7 + PP;
        const int par = ps & 1;

        if (ps <= NS - 2) commit(ps + 1);            // -> raw[(ps+1)&1]
        if (ps <= NS - 3) loadslice(ps + 2);         // in flight across barrier

        if (ps <= NS - 1) {                          // P2: raw[par] -> hb[par]
            p2item(par, q0r, q0w);
            if (q1on) p2item(par, q1r, q1w);
        }
        if (ps >= 1 && ps <= NS) {                   // P3: hb[par^1] -> window
            const int hp = par ^ 1;
            f32x2 a = {0.f, 0.f}, bv = {0.f, 0.f};
            #pragma unroll
            for (int k = 0; k < 7; ++k) {
                const float g = Gc[k];
                a  += g * hbA[hp][p4r][p4c + k];
                bv += g * hbB[hp][p4r][p4c + k];
            }
            wA[SLOT] = a; wB[SLOT] = bv;
            if (ps >= 7) {                           // emit od = ps-7
                f32x2 mu = {0.f, 0.f}, e2 = {0.f, 0.f};
                #pragma unroll
                for (int k = 0; k < 7; ++k) {
                    const int s = (PP + k) % 7;      // slice ps-7+k
                    const float g = Gc[k];
                    mu += g * wA[s]; e2 += g * wB[s];
                }
                const float P = mu.x * mu.x, Q = mu.y * mu.y;
                const float u  = 0.5f * (P + Q);     // mux^2 + muy^2
                const float v_ = 0.5f * (P - Q);     // 2 mux muy
                const float a2 = 0.5f * (e2.x + e2.y);
                const float b2 = 0.5f * (e2.x - e2.y);
                const float num = (v_ + C1f) * (b2 - v_ + C2f);
                const float den = (u  + C1f) * (a2 - u  + C2f);
                ssum += num * rcp_fast(den);
            }
        }
        STEP_BARRIER();
    };

    // prologue: slice 0 committed, slice 1 prefetched into regs
    loadslice(0);
    commit(0);
    loadslice(1);
    STEP_BARRIER();

    for (int it = 0; it < 4; ++it) {       // ps = 0..27 (27 is a no-op pad)
        phase(IC<0>{}, it); phase(IC<1>{}, it); phase(IC<2>{}, it);
        phase(IC<3>{}, it); phase(IC<4>{}, it); phase(IC<5>{}, it);
        phase(IC<6>{}, it);
    }

    // ---- block reduce + atomics ----
    #pragma unroll
    for (int off = 32; off > 0; off >>= 1) {
        ssum += __shfl_down(ssum, off, 64);
        l1n  += __shfl_down(l1n,  off, 64);
        l1d  += __shfl_down(l1d,  off, 64);
    }
    const int wave = t >> 6, lane = t & 63;
    if (lane == 0) { red[wave][0] = ssum; red[wave][1] = l1n; red[wave][2] = l1d; }
    __syncthreads();
    if (t == 0) {
        float s = 0.f, n = 0.f, dn = 0.f;
        #pragma unroll
        for (int i = 0; i < NTH / 64; ++i) {
            s += red[i][0]; n += red[i][1]; dn += red[i][2];
        }
        atomicAdd(&acc[0], s);
        atomicAdd(&acc[1], n);
        atomicAdd(&acc[2], dn);
    }
}

__global__ void nq_final(const float* __restrict__ acc,
                         const float* __restrict__ vq,
                         float* __restrict__ out)
{
    const float ssim_mean = acc[0] / (float)NTOT;
    out[0] = acc[1] / acc[2] + 0.5f * (1.0f - ssim_mean) + vq[0];
}

extern "C" void kernel_launch(void* const* d_in, const int* in_sizes, int n_in,
                              void* d_out, int out_size, void* d_ws, size_t ws_size,
                              hipStream_t stream)
{
    const float* X  = (const float*)d_in[0];  // recon
    const float* Y  = (const float*)d_in[1];  // target
    const float* vq = (const float*)d_in[2];  // scalar
    float* out = (float*)d_out;
    float* acc = (float*)d_ws;

    hipMemsetAsync(acc, 0, 3 * sizeof(float), stream);

    dim3 grid(WDIM / TW, HDIM / TH, BDIM * NSEG);   // 3 x 24 x 32 = 2304 blocks
    nq_main<<<grid, NTH, 0, stream>>>(X, Y, acc);
    nq_final<<<1, 1, 0, stream>>>(acc, vq, out);
}